// Round 4
// baseline (138.898 us; speedup 1.0000x reference)
//
#include <hip/hip_runtime.h>
#include <hip/hip_bf16.h>
#include <stdint.h>

#define S_LEN 2048
#define BATCH 4
#define HID 1024
#define M_ROWS (BATCH * S_LEN)   // 8192

typedef __attribute__((ext_vector_type(8))) short short8;
typedef __attribute__((ext_vector_type(4))) float f32x4;

__device__ __forceinline__ void gload_lds16(const __hip_bfloat16* g,
                                            __hip_bfloat16* l) {
  __builtin_amdgcn_global_load_lds(
      (const __attribute__((address_space(1))) unsigned int*)g,
      (__attribute__((address_space(3))) unsigned int*)l, 16, 0, 0);
}

template <int N>
__device__ __forceinline__ void wait_vm() {
  if constexpr (N == 0)
    asm volatile("s_waitcnt vmcnt(0)" ::: "memory");
  else if constexpr (N == 2)
    asm volatile("s_waitcnt vmcnt(2)" ::: "memory");
  else
    asm volatile("s_waitcnt vmcnt(4)" ::: "memory");
}

// ============ transpose-convert: Wq,Wk fp32 -> WqT,WkT bf16 ============
__global__ __launch_bounds__(256) void transpose_convert(
    const float* __restrict__ Wq, const float* __restrict__ Wk,
    __hip_bfloat16* __restrict__ WqT, __hip_bfloat16* __restrict__ WkT) {
  __shared__ float tile[32][33];
  const float* src = blockIdx.z ? Wk : Wq;
  __hip_bfloat16* dst = blockIdx.z ? WkT : WqT;
  const int tx = threadIdx.x & 31, ty = threadIdx.x >> 5;  // ty 0..7
  const int r0 = blockIdx.y * 32, c0 = blockIdx.x * 32;
#pragma unroll
  for (int rr = 0; rr < 4; ++rr) {
    const int r = ty + rr * 8;
    tile[r][tx] = src[(size_t)(r0 + r) * HID + c0 + tx];
  }
  __syncthreads();
#pragma unroll
  for (int rr = 0; rr < 4; ++rr) {
    const int r = ty + rr * 8;
    dst[(size_t)(c0 + r) * HID + r0 + tx] = __float2bfloat16(tile[tx][r]);
  }
}

// ===== bias stage 1 (fp32 direct): a1 = Wq^T bk, a2 = Wk^T bq, c=bq.bk ==
// grid (4,2) x 256: column sums, coalesced across threads.
__global__ __launch_bounds__(256) void bias_stage1(
    const float* __restrict__ Wq, const float* __restrict__ Wk,
    const float* __restrict__ bq, const float* __restrict__ bk,
    float* __restrict__ a1, float* __restrict__ a2, float* __restrict__ cbuf) {
  const int mat = blockIdx.y;
  const int j = blockIdx.x * 256 + threadIdx.x;
  const float* W = mat ? Wk : Wq;
  const float* bv = mat ? bq : bk;
  float s = 0.f;
  for (int i = 0; i < HID; ++i) s += W[(size_t)i * HID + j] * bv[i];
  (mat ? a2 : a1)[j] = s;
  if (blockIdx.x == 0 && mat == 0 && threadIdx.x < 64) {
    float cs = 0.f;
#pragma unroll
    for (int e = 0; e < 16; ++e)
      cs += bq[threadIdx.x * 16 + e] * bk[threadIdx.x * 16 + e];
#pragma unroll
    for (int m = 1; m < 64; m <<= 1) cs += __shfl_xor(cs, m, 64);
    if (threadIdx.x == 0) cbuf[0] = cs;
  }
}

// ===== convert hs -> bf16, plus u = hs.a1 + c (row term), w = hs.a2 =====
__global__ __launch_bounds__(256) void convert_hs(
    const float* __restrict__ hs, const float* __restrict__ a1,
    const float* __restrict__ a2, const float* __restrict__ cbuf,
    __hip_bfloat16* __restrict__ hs_bf, float* __restrict__ u,
    float* __restrict__ w) {
  const int i = blockIdx.x;
  const int t = threadIdx.x;
  float4 v = *reinterpret_cast<const float4*>(hs + (size_t)i * HID + t * 4);
  __hip_bfloat16 tmp[4] = {__float2bfloat16(v.x), __float2bfloat16(v.y),
                           __float2bfloat16(v.z), __float2bfloat16(v.w)};
  *reinterpret_cast<ushort4*>(hs_bf + (size_t)i * HID + t * 4) =
      *reinterpret_cast<const ushort4*>(tmp);
  float4 A1 = *reinterpret_cast<const float4*>(a1 + t * 4);
  float4 A2 = *reinterpret_cast<const float4*>(a2 + t * 4);
  float pu = v.x * A1.x + v.y * A1.y + v.z * A1.z + v.w * A1.w;
  float pw = v.x * A2.x + v.y * A2.y + v.z * A2.z + v.w * A2.w;
#pragma unroll
  for (int m = 1; m < 64; m <<= 1) {
    pu += __shfl_xor(pu, m, 64);
    pw += __shfl_xor(pw, m, 64);
  }
  __shared__ float su[4], sw[4];
  if ((t & 63) == 0) { su[t >> 6] = pu; sw[t >> 6] = pw; }
  __syncthreads();
  if (t == 0) {
    u[i] = su[0] + su[1] + su[2] + su[3] + cbuf[0];
    w[i] = sw[0] + sw[1] + sw[2] + sw[3];
  }
}

// ================= templated 8-phase NT GEMM core =====================
// BM=256; BN = NF*64. 512 thr = 8 waves (2 M x 4 N). Double-buffered LDS,
// XOR-swizzle both sides, counted vmcnt, setprio. MFMA operands SWAPPED
// (fb first) so acc[m][n] lane-layout is: row = m*16+(l&15),
// col = n*16+(l>>4)*4+r  -> 4 consecutive COLS per lane = vector stores.
template <int NT, int NF>
__device__ __forceinline__ void gemm_core(
    const __hip_bfloat16* __restrict__ A, const __hip_bfloat16* __restrict__ B,
    const int lda, const int ldb, __hip_bfloat16* lds, f32x4 acc[8][NF]) {
  constexpr int NH = NF / 2;
  const int t = threadIdx.x;
  const int wid = t >> 6;
  const int l = t & 63;
  const int lr = l & 15;
  const int lk = l >> 4;
  const int wr = wid >> 2;
  const int wc = wid & 3;
  const int trow = t >> 3;
  const int tslot = (t & 7) ^ (trow & 7);
  const int rsx = lr & 7;

  __hip_bfloat16* const A0 = lds;
  __hip_bfloat16* const A1 = lds + 16384;
  __hip_bfloat16* const B0 = lds + 32768;
  __hip_bfloat16* const B1 = B0 + NF * 64 * 64;

  short8 fa[4][2], fb[NF][2];

#define STAGE_U(lb, gb, ld, half, kt) do {                                    \
    gload_lds16((gb) + (size_t)((half)*128 + 0  + trow) * (ld) + (kt)*64 +    \
                    tslot * 8,                                                \
                (lb) + ((half)*128 + 0) * 64 + wid * 512);                    \
    gload_lds16((gb) + (size_t)((half)*128 + 64 + trow) * (ld) + (kt)*64 +    \
                    tslot * 8,                                                \
                (lb) + ((half)*128 + 64) * 64 + wid * 512);                   \
  } while (0)

#define LDA_H(mh, Ac) do {                                                    \
    _Pragma("unroll") for (int m = 0; m < 4; ++m)                             \
    _Pragma("unroll") for (int kk = 0; kk < 2; ++kk)                          \
      fa[m][kk] = *reinterpret_cast<const short8*>(                           \
          (Ac) + (wr * 128 + (mh)*64 + m * 16 + lr) * 64 +                    \
          (((kk * 4 + lk) ^ rsx) * 8));                                       \
  } while (0)

#define LDB_H(nh, Bc) do {                                                    \
    _Pragma("unroll") for (int n = 0; n < NH; ++n)                            \
    _Pragma("unroll") for (int kk = 0; kk < 2; ++kk)                          \
      fb[(nh)*NH + n][kk] = *reinterpret_cast<const short8*>(                 \
          (Bc) + (wc * (NF * 16) + (nh) * (NH * 16) + n * 16 + lr) * 64 +     \
          (((kk * 4 + lk) ^ rsx) * 8));                                       \
  } while (0)

#define MFMA_Q(mh, nh) do {                                                   \
    __builtin_amdgcn_s_setprio(1);                                            \
    _Pragma("unroll") for (int m = 0; m < 4; ++m)                             \
    _Pragma("unroll") for (int n = 0; n < NH; ++n)                            \
    _Pragma("unroll") for (int kk = 0; kk < 2; ++kk)                          \
      acc[(mh)*4 + m][(nh)*NH + n] = __builtin_amdgcn_mfma_f32_16x16x32_bf16( \
          fb[(nh)*NH + n][kk], fa[m][kk], acc[(mh)*4 + m][(nh)*NH + n],       \
          0, 0, 0);                                                           \
    __builtin_amdgcn_s_setprio(0);                                            \
  } while (0)

#define CFENCE asm volatile("" ::: "memory")
#define BAR_PRE do { CFENCE; __builtin_amdgcn_s_barrier();                    \
    asm volatile("s_waitcnt lgkmcnt(0)" ::: "memory"); } while (0)
#define BAR_POST do { CFENCE; __builtin_amdgcn_s_barrier(); CFENCE; } while (0)

  // prologue: tile0 fully, tile1 B
  STAGE_U(A0, A, lda, 0, 0); STAGE_U(A0, A, lda, 1, 0);
  STAGE_U(B0, B, ldb, 0, 0); if (NH == 2) STAGE_U(B0, B, ldb, 1, 0);
  STAGE_U(B1, B, ldb, 0, 1); if (NH == 2) STAGE_U(B1, B, ldb, 1, 1);
  wait_vm<2 * NH>();
  __builtin_amdgcn_s_barrier();
  CFENCE;

#pragma unroll 2
  for (int tt = 0; tt < NT; ++tt) {
    const int cur = tt & 1;
    __hip_bfloat16* const Ac = cur ? A1 : A0;
    __hip_bfloat16* const An = cur ? A0 : A1;
    __hip_bfloat16* const Bc = cur ? B1 : B0;
    // c0
    LDA_H(0, Ac); LDB_H(0, Bc);
    if (tt + 1 < NT) STAGE_U(An, A, lda, 0, tt + 1);
    BAR_PRE; MFMA_Q(0, 0); BAR_POST;
    // c1
    LDB_H(1, Bc);
    if (tt + 1 < NT) STAGE_U(An, A, lda, 1, tt + 1);
    BAR_PRE; MFMA_Q(0, 1); BAR_POST;
    // c2
    LDA_H(1, Ac);
    if (tt + 2 < NT) STAGE_U(Bc, B, ldb, 0, tt + 2);
    BAR_PRE; MFMA_Q(1, 1); BAR_POST;
    // c3 (tail: drain fully so next tile's A never races)
    if (NH == 2 && tt + 2 < NT) STAGE_U(Bc, B, ldb, 1, tt + 2);
    BAR_PRE; MFMA_Q(1, 0);
    if (tt + 2 < NT) wait_vm<2 * NH>(); else wait_vm<0>();
    BAR_POST;
  }
#undef STAGE_U
#undef LDA_H
#undef LDB_H
#undef MFMA_Q
#undef CFENCE
#undef BAR_PRE
#undef BAR_POST
}

// ===== wmid partial: part[kz] = (Wk^T Wq) slab, via WkT . WqT^T ======
// grid (4,4,4)
__global__ __launch_bounds__(512, 2) void wmid_gemm(
    const __hip_bfloat16* __restrict__ WkT,
    const __hip_bfloat16* __restrict__ WqT, float* __restrict__ part) {
  extern __shared__ char smem[];
  __hip_bfloat16* lds = reinterpret_cast<__hip_bfloat16*>(smem);
  const int kz = blockIdx.z;
  f32x4 acc[8][4];
#pragma unroll
  for (int m = 0; m < 8; ++m)
#pragma unroll
    for (int n = 0; n < 4; ++n) acc[m][n] = (f32x4){0.f, 0.f, 0.f, 0.f};

  gemm_core<4, 4>(WkT + (size_t)blockIdx.y * 256 * HID + kz * 256,
                  WqT + (size_t)blockIdx.x * 256 * HID + kz * 256, HID, HID,
                  lds, acc);

  float* outp = part + (size_t)kz * (HID * HID);
  const int t = threadIdx.x, wid = t >> 6, l = t & 63;
  const int wr = wid >> 2, wcn = wid & 3;
  const int lr = l & 15, lg = l >> 4;
#pragma unroll
  for (int m = 0; m < 8; ++m) {
    const int row = blockIdx.y * 256 + wr * 128 + m * 16 + lr;
#pragma unroll
    for (int n = 0; n < 4; ++n) {
      const int col = blockIdx.x * 256 + wcn * 64 + n * 16 + lg * 4;
      f32x4 a = acc[m][n];
      *reinterpret_cast<float4*>(&outp[(size_t)row * HID + col]) =
          (float4){a[0], a[1], a[2], a[3]};
    }
  }
}

// ============ reduce 4 slabs -> wmid bf16 ============
__global__ __launch_bounds__(256) void wmid_reduce(
    const float* __restrict__ part, __hip_bfloat16* __restrict__ wmid_bf) {
  const int idx = (blockIdx.x * 256 + threadIdx.x) * 4;
  float4 s0 = *reinterpret_cast<const float4*>(part + idx);
  float4 s1 = *reinterpret_cast<const float4*>(part + (HID * HID) + idx);
  float4 s2 = *reinterpret_cast<const float4*>(part + 2 * (HID * HID) + idx);
  float4 s3 = *reinterpret_cast<const float4*>(part + 3 * (HID * HID) + idx);
  __hip_bfloat16 tmp[4] = {__float2bfloat16(s0.x + s1.x + s2.x + s3.x),
                           __float2bfloat16(s0.y + s1.y + s2.y + s3.y),
                           __float2bfloat16(s0.z + s1.z + s2.z + s3.z),
                           __float2bfloat16(s0.w + s1.w + s2.w + s3.w)};
  *reinterpret_cast<ushort4*>(wmid_bf + idx) =
      *reinterpret_cast<const ushort4*>(tmp);
}

// ============ T = hs @ Wmid  (NF=2: 256x128 tiles) ============
__global__ __launch_bounds__(512, 2) void t_gemm(
    const __hip_bfloat16* __restrict__ hs_bf,
    const __hip_bfloat16* __restrict__ wmid_bf,
    __hip_bfloat16* __restrict__ T) {
  extern __shared__ char smem[];
  __hip_bfloat16* lds = reinterpret_cast<__hip_bfloat16*>(smem);
  f32x4 acc[8][2];
#pragma unroll
  for (int m = 0; m < 8; ++m)
#pragma unroll
    for (int n = 0; n < 2; ++n) acc[m][n] = (f32x4){0.f, 0.f, 0.f, 0.f};

  gemm_core<16, 2>(hs_bf + (size_t)blockIdx.y * 256 * HID,
                   wmid_bf + (size_t)blockIdx.x * 128 * HID, HID, HID, lds,
                   acc);

  const int t = threadIdx.x, wid = t >> 6, l = t & 63;
  const int wr = wid >> 2, wcn = wid & 3;
  const int lr = l & 15, lg = l >> 4;
#pragma unroll
  for (int m = 0; m < 8; ++m) {
    const int row = blockIdx.y * 256 + wr * 128 + m * 16 + lr;
#pragma unroll
    for (int n = 0; n < 2; ++n) {
      const int col = blockIdx.x * 128 + wcn * 32 + n * 16 + lg * 4;
      f32x4 a = acc[m][n];
      __hip_bfloat16 tmp[4] = {__float2bfloat16(a[0]), __float2bfloat16(a[1]),
                               __float2bfloat16(a[2]), __float2bfloat16(a[3])};
      *reinterpret_cast<ushort4*>(&T[(size_t)row * HID + col]) =
          *reinterpret_cast<const ushort4*>(tmp);
    }
  }
}

// ====== scores: out[b] = (T hs^T + u 1^T + 1 w^T)/128 * masks ==========
// 1-D grid 256; XCD-chunk swizzle: xcd = bid&7 owns a 2bm x 4bn chunk/batch
__global__ __launch_bounds__(512, 2) void scores_gemm(
    const __hip_bfloat16* __restrict__ T, const __hip_bfloat16* __restrict__ hs_bf,
    const float* __restrict__ mask, const float* __restrict__ u,
    const float* __restrict__ w, float* __restrict__ out) {
  extern __shared__ char smem[];
  __hip_bfloat16* lds = reinterpret_cast<__hip_bfloat16*>(smem);
  const int bid = blockIdx.x;
  const int xcd = bid & 7, slot = bid >> 3;
  const int b = slot >> 3, sub = slot & 7;
  const int bm = (xcd & 3) * 2 + (sub >> 2);
  const int bn = (xcd >> 2) * 4 + (sub & 3);

  f32x4 acc[8][4];
#pragma unroll
  for (int m = 0; m < 8; ++m)
#pragma unroll
    for (int n = 0; n < 4; ++n) acc[m][n] = (f32x4){0.f, 0.f, 0.f, 0.f};

  gemm_core<16, 4>(T + ((size_t)b * S_LEN + bm * 256) * HID,
                   hs_bf + ((size_t)b * S_LEN + bn * 256) * HID, HID, HID,
                   lds, acc);

  const int t = threadIdx.x, wid = t >> 6, l = t & 63;
  const int wr = wid >> 2, wcn = wid & 3;
  const int lr = l & 15, lg = l >> 4;
  const float inv = 1.0f / 128.0f;   // 1/sqrt(64) * 1/16 heads
#pragma unroll
  for (int m = 0; m < 8; ++m) {
    const int row = bm * 256 + wr * 128 + m * 16 + lr;
    const float mr = mask[b * S_LEN + row] * inv;
    const float uadd = u[b * S_LEN + row];
#pragma unroll
    for (int n = 0; n < 4; ++n) {
      const int col = bn * 256 + wcn * 64 + n * 16 + lg * 4;
      float4 mcv = *reinterpret_cast<const float4*>(&mask[b * S_LEN + col]);
      float4 wv = *reinterpret_cast<const float4*>(&w[b * S_LEN + col]);
      f32x4 a = acc[m][n];
      float4 o = {(a[0] + uadd + wv.x) * mr * mcv.x,
                  (a[1] + uadd + wv.y) * mr * mcv.y,
                  (a[2] + uadd + wv.z) * mr * mcv.z,
                  (a[3] + uadd + wv.w) * mr * mcv.w};
      *reinterpret_cast<float4*>(
          &out[(size_t)b * S_LEN * S_LEN + (size_t)row * S_LEN + col]) = o;
    }
  }
}

extern "C" void kernel_launch(void* const* d_in, const int* in_sizes, int n_in,
                              void* d_out, int out_size, void* d_ws,
                              size_t ws_size, hipStream_t stream) {
  const float* hs   = (const float*)d_in[0];
  const float* mask = (const float*)d_in[1];
  const float* Wq   = (const float*)d_in[2];
  const float* bq   = (const float*)d_in[3];
  const float* Wk   = (const float*)d_in[4];
  const float* bk   = (const float*)d_in[5];
  float* out = (float*)d_out;

  char* ws = (char*)d_ws;
  __hip_bfloat16* hs_bf   = (__hip_bfloat16*)(ws);               // 16 MB
  float*          wmid_p  = (float*)(ws + 16777216);             // 16 MB (steps 4-5)
  __hip_bfloat16* T_bf    = (__hip_bfloat16*)(ws + 16777216);    // same region (steps 6-7)
  __hip_bfloat16* WqT     = (__hip_bfloat16*)(ws + 33554432);    //  2 MB
  __hip_bfloat16* WkT     = (__hip_bfloat16*)(ws + 35651584);    //  2 MB
  __hip_bfloat16* wmid_bf = (__hip_bfloat16*)(ws + 37748736);    //  2 MB
  float*          a1      = (float*)(ws + 39845888);             //  4 KB
  float*          a2      = (float*)(ws + 39849984);             //  4 KB
  float*          cbuf    = (float*)(ws + 39854080);             //  4 KB
  float*          uvec    = (float*)(ws + 39858176);             // 32 KB
  float*          wvec    = (float*)(ws + 39890944);             // 32 KB

  (void)hipFuncSetAttribute((const void*)wmid_gemm,
                            hipFuncAttributeMaxDynamicSharedMemorySize, 131072);
  (void)hipFuncSetAttribute((const void*)t_gemm,
                            hipFuncAttributeMaxDynamicSharedMemorySize, 98304);
  (void)hipFuncSetAttribute((const void*)scores_gemm,
                            hipFuncAttributeMaxDynamicSharedMemorySize, 131072);

  hipLaunchKernelGGL(bias_stage1, dim3(4, 2), dim3(256), 0, stream,
                     Wq, Wk, bq, bk, a1, a2, cbuf);
  hipLaunchKernelGGL(transpose_convert, dim3(32, 32, 2), dim3(256), 0, stream,
                     Wq, Wk, WqT, WkT);
  hipLaunchKernelGGL(convert_hs, dim3(M_ROWS), dim3(256), 0, stream,
                     hs, a1, a2, cbuf, hs_bf, uvec, wvec);
  hipLaunchKernelGGL(wmid_gemm, dim3(4, 4, 4), dim3(512), 131072, stream,
                     WkT, WqT, wmid_p);
  hipLaunchKernelGGL(wmid_reduce, dim3(1024), dim3(256), 0, stream,
                     wmid_p, wmid_bf);
  hipLaunchKernelGGL(t_gemm, dim3(HID / 128, M_ROWS / 256), dim3(512), 98304,
                     stream, hs_bf, wmid_bf, T_bf);
  hipLaunchKernelGGL(scores_gemm, dim3(256), dim3(512), 131072, stream,
                     T_bf, hs_bf, mask, uvec, wvec, out);
}

// Round 5
// 98.647 us; speedup vs baseline: 1.4080x; 1.4080x over previous
//
#include <hip/hip_runtime.h>
#include <hip/hip_bf16.h>
#include <stdint.h>

#define S_LEN 2048
#define BATCH 4
#define HID 1024
#define M_ROWS (BATCH * S_LEN)   // 8192

typedef __attribute__((ext_vector_type(8))) short short8;
typedef __attribute__((ext_vector_type(16))) float f32x16;

__device__ __forceinline__ void gload_lds16(const __hip_bfloat16* g,
                                            __hip_bfloat16* l) {
  __builtin_amdgcn_global_load_lds(
      (const __attribute__((address_space(1))) unsigned int*)g,
      (__attribute__((address_space(3))) unsigned int*)l, 16, 0, 0);
}

template <int N>
__device__ __forceinline__ void wait_vm() {
  if constexpr (N == 0)
    asm volatile("s_waitcnt vmcnt(0)" ::: "memory");
  else
    asm volatile("s_waitcnt vmcnt(4)" ::: "memory");
}

// ---------------- fp32 -> bf16 conversion (hs, Wq, Wk) ----------------
__global__ __launch_bounds__(256) void convert_all(
    const float* __restrict__ hs, const float* __restrict__ wq,
    const float* __restrict__ wk,
    __hip_bfloat16* __restrict__ hs_bf, __hip_bfloat16* __restrict__ wq_bf,
    __hip_bfloat16* __restrict__ wk_bf) {
  const int NH = M_ROWS * HID;   // 8388608
  const int NW = HID * HID;      // 1048576
  int idx = (blockIdx.x * blockDim.x + threadIdx.x) * 4;
  const float* src;
  __hip_bfloat16* dst;
  int off;
  if (idx < NH)           { src = hs; dst = hs_bf; off = idx; }
  else if (idx < NH + NW) { src = wq; dst = wq_bf; off = idx - NH; }
  else                    { src = wk; dst = wk_bf; off = idx - NH - NW; }
  float4 v = *reinterpret_cast<const float4*>(src + off);
  __hip_bfloat16 tmp[4];
  tmp[0] = __float2bfloat16(v.x);
  tmp[1] = __float2bfloat16(v.y);
  tmp[2] = __float2bfloat16(v.z);
  tmp[3] = __float2bfloat16(v.w);
  *reinterpret_cast<ushort4*>(dst + off) = *reinterpret_cast<const ushort4*>(tmp);
}

// =========== 256x256 4-phase NT GEMM core, 32x32x16 MFMA ==============
// 512 thr = 8 waves (2 M x 4 N); per-wave 128x64 via 4x2 frags of 32x32.
// BK=64 double-buffered LDS (128 KiB), XOR-swizzled 16B slots both sides,
// counted vmcnt(4), raw s_barrier, setprio around MFMA clusters.
// A-frag: row = l&31, k = (l>>5)*8+e.  C/D: col = l&31,
// row = (reg&3)+8*(reg>>2)+4*(l>>5)  [m74/m101-verified].
template <int NT>
__device__ __forceinline__ void gemm_core32(
    const __hip_bfloat16* __restrict__ A, const __hip_bfloat16* __restrict__ B,
    const int lda, const int ldb, __hip_bfloat16* lds, f32x16 acc[4][2]) {
  const int t = threadIdx.x;
  const int wid = t >> 6;
  const int l = t & 63;
  const int lr32 = l & 31;     // row within 32-frag
  const int hk = l >> 5;       // k-half selector
  const int wr = wid >> 2;     // wave row 0..1 (128 rows each)
  const int wc = wid & 3;      // wave col 0..3 (64 cols each)
  const int trow = t >> 3;
  const int tslot = (t & 7) ^ (trow & 7);  // pre-swizzled global 16B slot
  const int rsx = lr32 & 7;    // read-side xor (row&7)

  __hip_bfloat16* const A0 = lds;
  __hip_bfloat16* const A1 = lds + 16384;
  __hip_bfloat16* const B0 = lds + 32768;
  __hip_bfloat16* const B1 = lds + 49152;

  short8 fa[2][4], fb[2][4];

#define STAGE_U(lb, gb, ld, half, kt) do {                                    \
    gload_lds16((gb) + (size_t)((half)*128 + 0  + trow) * (ld) + (kt)*64 +    \
                    tslot * 8,                                                \
                (lb) + ((half)*128 + 0) * 64 + wid * 512);                    \
    gload_lds16((gb) + (size_t)((half)*128 + 64 + trow) * (ld) + (kt)*64 +    \
                    tslot * 8,                                                \
                (lb) + ((half)*128 + 64) * 64 + wid * 512);                   \
  } while (0)

// load 2 m-frags (mh half), all 4 k-slices
#define LDA2(mh, Ac) do {                                                     \
    _Pragma("unroll") for (int mm = 0; mm < 2; ++mm)                          \
    _Pragma("unroll") for (int kk = 0; kk < 4; ++kk)                          \
      fa[mm][kk] = *reinterpret_cast<const short8*>(                          \
          (Ac) + (wr * 128 + ((mh)*2 + mm) * 32 + lr32) * 64 +                \
          (((kk * 2 + hk) ^ rsx) * 8));                                       \
  } while (0)

// load 1 n-frag (nh), all 4 k-slices
#define LDB1(nh, Bc) do {                                                     \
    _Pragma("unroll") for (int kk = 0; kk < 4; ++kk)                          \
      fb[nh][kk] = *reinterpret_cast<const short8*>(                          \
          (Bc) + (wc * 64 + (nh)*32 + lr32) * 64 +                            \
          (((kk * 2 + hk) ^ rsx) * 8));                                       \
  } while (0)

#define MFMA_Q(mh, nh) do {                                                   \
    __builtin_amdgcn_s_setprio(1);                                            \
    _Pragma("unroll") for (int mm = 0; mm < 2; ++mm)                          \
    _Pragma("unroll") for (int kk = 0; kk < 4; ++kk)                          \
      acc[(mh)*2 + mm][nh] = __builtin_amdgcn_mfma_f32_32x32x16_bf16(         \
          fa[mm][kk], fb[nh][kk], acc[(mh)*2 + mm][nh], 0, 0, 0);             \
    __builtin_amdgcn_s_setprio(0);                                            \
  } while (0)

#define CFENCE asm volatile("" ::: "memory")
#define BAR_PRE do { CFENCE; __builtin_amdgcn_s_barrier();                    \
    asm volatile("s_waitcnt lgkmcnt(0)" ::: "memory"); } while (0)
#define BAR_POST do { CFENCE; __builtin_amdgcn_s_barrier(); CFENCE; } while (0)

  // prologue: tile0 fully, tile1 B
  STAGE_U(A0, A, lda, 0, 0); STAGE_U(A0, A, lda, 1, 0);
  STAGE_U(B0, B, ldb, 0, 0); STAGE_U(B0, B, ldb, 1, 0);
  STAGE_U(B1, B, ldb, 0, 1); STAGE_U(B1, B, ldb, 1, 1);
  wait_vm<4>();
  __builtin_amdgcn_s_barrier();
  CFENCE;

#pragma unroll 2
  for (int tt = 0; tt < NT; ++tt) {
    const int cur = tt & 1;
    __hip_bfloat16* const Ac = cur ? A1 : A0;
    __hip_bfloat16* const An = cur ? A0 : A1;
    __hip_bfloat16* const Bc = cur ? B1 : B0;
    // c0: m-frags 0,1 x n-frag 0
    LDA2(0, Ac); LDB1(0, Bc);
    if (tt + 1 < NT) STAGE_U(An, A, lda, 0, tt + 1);
    BAR_PRE; MFMA_Q(0, 0); BAR_POST;
    // c1: m-frags 0,1 x n-frag 1
    LDB1(1, Bc);
    if (tt + 1 < NT) STAGE_U(An, A, lda, 1, tt + 1);
    BAR_PRE; MFMA_Q(0, 1); BAR_POST;
    // c2: m-frags 2,3 x n-frag 1 (fb[1] live; fa overwritten)
    LDA2(1, Ac);
    if (tt + 2 < NT) STAGE_U(Bc, B, ldb, 0, tt + 2);
    BAR_PRE; MFMA_Q(1, 1); BAR_POST;
    // c3: m-frags 2,3 x n-frag 0 (fb[0] live since c0)
    if (tt + 2 < NT) STAGE_U(Bc, B, ldb, 1, tt + 2);
    BAR_PRE; MFMA_Q(1, 0);
    if (tt + 2 < NT) wait_vm<4>(); else wait_vm<0>();
    BAR_POST;
  }
#undef STAGE_U
#undef LDA2
#undef LDB1
#undef MFMA_Q
#undef CFENCE
#undef BAR_PRE
#undef BAR_POST
}

// ---------------- Q/K projection: X @ W^T + b -> bf16 ----------------
// 1-D grid 256, XCD swizzle: xcd owns 4 consecutive bm panels (A reuse).
__global__ __launch_bounds__(512, 2) void proj_gemm(
    const __hip_bfloat16* __restrict__ X,
    const __hip_bfloat16* __restrict__ Wq, const float* __restrict__ bq,
    const __hip_bfloat16* __restrict__ Wk, const float* __restrict__ bk,
    __hip_bfloat16* __restrict__ Qo, __hip_bfloat16* __restrict__ Ko) {
  extern __shared__ char smem[];
  __hip_bfloat16* lds = reinterpret_cast<__hip_bfloat16*>(smem);
  const int bid = blockIdx.x;
  const int xcd = bid & 7, s = bid >> 3;       // s in 0..31
  const int bm = xcd * 4 + (s & 3);            // 0..31
  const int bn8 = s >> 2;                      // 0..7
  const int z = bn8 >> 2;                      // 0: Q, 1: K
  const int bn = bn8 & 3;                      // 0..3

  const __hip_bfloat16* W = z ? Wk : Wq;
  const float* bias = z ? bk : bq;
  __hip_bfloat16* Out = z ? Ko : Qo;

  f32x16 acc[4][2];
#pragma unroll
  for (int mi = 0; mi < 4; ++mi)
#pragma unroll
    for (int ni = 0; ni < 2; ++ni)
#pragma unroll
      for (int e = 0; e < 16; ++e) acc[mi][ni][e] = 0.f;

  gemm_core32<HID / 64>(X + (size_t)bm * 256 * HID,
                        W + (size_t)bn * 256 * HID, HID, HID, lds, acc);

  const int t = threadIdx.x, wid = t >> 6, l = t & 63;
  const int wr = wid >> 2, wc = wid & 3;
  const int lr32 = l & 31, hk = l >> 5;
#pragma unroll
  for (int ni = 0; ni < 2; ++ni) {
    const int col = bn * 256 + wc * 64 + ni * 32 + lr32;
    const float bb = bias[col];
#pragma unroll
    for (int mi = 0; mi < 4; ++mi) {
#pragma unroll
      for (int reg = 0; reg < 16; ++reg) {
        const int row =
            bm * 256 + wr * 128 + mi * 32 + (reg & 3) + 8 * (reg >> 2) + 4 * hk;
        Out[(size_t)row * HID + col] = __float2bfloat16(acc[mi][ni][reg] + bb);
      }
    }
  }
}

// ---------- scores: out[b] = (Q K^T / 128) * mask_r * mask_c ----------
// 1-D grid 256; XCD-chunk swizzle (r4-validated decode).
__global__ __launch_bounds__(512, 2) void scores_gemm(
    const __hip_bfloat16* __restrict__ Q, const __hip_bfloat16* __restrict__ Km,
    const float* __restrict__ mask, float* __restrict__ out) {
  extern __shared__ char smem[];
  __hip_bfloat16* lds = reinterpret_cast<__hip_bfloat16*>(smem);
  const int bid = blockIdx.x;
  const int xcd = bid & 7, slot = bid >> 3;
  const int b = slot >> 3, sub = slot & 7;
  const int bm = (xcd & 3) * 2 + (sub >> 2);
  const int bn = (xcd >> 2) * 4 + (sub & 3);

  f32x16 acc[4][2];
#pragma unroll
  for (int mi = 0; mi < 4; ++mi)
#pragma unroll
    for (int ni = 0; ni < 2; ++ni)
#pragma unroll
      for (int e = 0; e < 16; ++e) acc[mi][ni][e] = 0.f;

  gemm_core32<HID / 64>(Q + ((size_t)b * S_LEN + bm * 256) * HID,
                        Km + ((size_t)b * S_LEN + bn * 256) * HID, HID, HID,
                        lds, acc);

  const int t = threadIdx.x, wid = t >> 6, l = t & 63;
  const int wr = wid >> 2, wc = wid & 3;
  const int lr32 = l & 31, hk = l >> 5;
  const float inv = 1.0f / 128.0f;   // 1/sqrt(64) * 1/16 heads
#pragma unroll
  for (int ni = 0; ni < 2; ++ni) {
    const int col = bn * 256 + wc * 64 + ni * 32 + lr32;
    const float mc = mask[b * S_LEN + col];
#pragma unroll
    for (int mi = 0; mi < 4; ++mi) {
#pragma unroll
      for (int reg = 0; reg < 16; ++reg) {
        const int row =
            bm * 256 + wr * 128 + mi * 32 + (reg & 3) + 8 * (reg >> 2) + 4 * hk;
        const float mr = mask[b * S_LEN + row];
        out[(size_t)b * S_LEN * S_LEN + (size_t)row * S_LEN + col] =
            acc[mi][ni][reg] * inv * mr * mc;
      }
    }
  }
}

extern "C" void kernel_launch(void* const* d_in, const int* in_sizes, int n_in,
                              void* d_out, int out_size, void* d_ws,
                              size_t ws_size, hipStream_t stream) {
  const float* hs   = (const float*)d_in[0];
  const float* mask = (const float*)d_in[1];
  const float* Wq   = (const float*)d_in[2];
  const float* bq   = (const float*)d_in[3];
  const float* Wk   = (const float*)d_in[4];
  const float* bk   = (const float*)d_in[5];
  float* out = (float*)d_out;

  char* ws = (char*)d_ws;
  __hip_bfloat16* hs_bf = (__hip_bfloat16*)(ws);                 // 16 MB
  __hip_bfloat16* wq_bf = (__hip_bfloat16*)(ws + 16777216);      //  2 MB
  __hip_bfloat16* wk_bf = (__hip_bfloat16*)(ws + 18874368);      //  2 MB
  __hip_bfloat16* q_bf  = (__hip_bfloat16*)(ws + 20971520);      // 16 MB
  __hip_bfloat16* k_bf  = (__hip_bfloat16*)(ws + 37748736);      // 16 MB

  (void)hipFuncSetAttribute((const void*)proj_gemm,
                            hipFuncAttributeMaxDynamicSharedMemorySize, 131072);
  (void)hipFuncSetAttribute((const void*)scores_gemm,
                            hipFuncAttributeMaxDynamicSharedMemorySize, 131072);

  hipLaunchKernelGGL(convert_all, dim3(10240), dim3(256), 0, stream,
                     hs, Wq, Wk, hs_bf, wq_bf, wk_bf);
  hipLaunchKernelGGL(proj_gemm, dim3(256), dim3(512), 131072, stream,
                     hs_bf, wq_bf, bq, wk_bf, bk, q_bf, k_bf);
  hipLaunchKernelGGL(scores_gemm, dim3(256), dim3(512), 131072, stream,
                     q_bf, k_bf, mask, out);
}

// Round 7
// 96.504 us; speedup vs baseline: 1.4393x; 1.0222x over previous
//
#include <hip/hip_runtime.h>
#include <hip/hip_bf16.h>
#include <stdint.h>

#define S_LEN 2048
#define BATCH 4
#define HID 1024
#define M_ROWS (BATCH * S_LEN)   // 8192

typedef __attribute__((ext_vector_type(8))) short short8;
typedef __attribute__((ext_vector_type(4))) float f32x4;

__device__ __forceinline__ void gload_lds16(const void* g, void* l) {
  __builtin_amdgcn_global_load_lds(
      (const __attribute__((address_space(1))) unsigned int*)g,
      (__attribute__((address_space(3))) unsigned int*)l, 16, 0, 0);
}

template <int N>
__device__ __forceinline__ void wait_vm() {
  if constexpr (N == 0)
    asm volatile("s_waitcnt vmcnt(0)" ::: "memory");
  else
    asm volatile("s_waitcnt vmcnt(4)" ::: "memory");
}

#define CFENCE asm volatile("" ::: "memory")
#define BAR_PRE do { CFENCE; __builtin_amdgcn_s_barrier();                    \
    asm volatile("s_waitcnt lgkmcnt(0)" ::: "memory"); } while (0)
#define BAR_POST do { CFENCE; __builtin_amdgcn_s_barrier(); CFENCE; } while (0)

// ---------------- fp32 -> bf16 conversion (hs, Wq, Wk) ----------------
__global__ __launch_bounds__(256) void convert_all(
    const float* __restrict__ hs, const float* __restrict__ wq,
    const float* __restrict__ wk,
    __hip_bfloat16* __restrict__ hs_bf, __hip_bfloat16* __restrict__ wq_bf,
    __hip_bfloat16* __restrict__ wk_bf) {
  const int NH = M_ROWS * HID;
  const int NW = HID * HID;
  int idx = (blockIdx.x * blockDim.x + threadIdx.x) * 4;
  const float* src;
  __hip_bfloat16* dst;
  int off;
  if (idx < NH)           { src = hs; dst = hs_bf; off = idx; }
  else if (idx < NH + NW) { src = wq; dst = wq_bf; off = idx - NH; }
  else                    { src = wk; dst = wk_bf; off = idx - NH - NW; }
  float4 v = *reinterpret_cast<const float4*>(src + off);
  __hip_bfloat16 tmp[4];
  tmp[0] = __float2bfloat16(v.x);
  tmp[1] = __float2bfloat16(v.y);
  tmp[2] = __float2bfloat16(v.z);
  tmp[3] = __float2bfloat16(v.w);
  *reinterpret_cast<ushort4*>(dst + off) = *reinterpret_cast<const ushort4*>(tmp);
}

// ========= bf16 256x256 4-phase NT GEMM core (r4/r6-validated) ========
// 512 thr = 8 waves (2Mx4N); per-wave 128x64; BK=64 dbuf LDS 128KB;
// XOR-swizzled 16B slots both sides; counted vmcnt(4); MFMA SWAPPED
// (fb first): acc[m][n] lane layout row = m*16+(l&15),
// col = n*16+(l>>4)*4+r  -> 4 consecutive cols/lane = vector stores.
template <int NT>
__device__ __forceinline__ void gemm_core_bf(
    const __hip_bfloat16* __restrict__ A, const __hip_bfloat16* __restrict__ B,
    const int lda, const int ldb, __hip_bfloat16* lds, f32x4 acc[8][4]) {
  const int t = threadIdx.x;
  const int wid = t >> 6;
  const int l = t & 63;
  const int lr = l & 15;
  const int lk = l >> 4;
  const int wr = wid >> 2;
  const int wc = wid & 3;
  const int trow = t >> 3;
  const int tslot = (t & 7) ^ (trow & 7);
  const int rsx = lr & 7;

  __hip_bfloat16* const A0 = lds;
  __hip_bfloat16* const A1 = lds + 16384;
  __hip_bfloat16* const B0 = lds + 32768;
  __hip_bfloat16* const B1 = lds + 49152;

  short8 fa[4][2], fb[4][2];

#define STAGE_U(lb, gb, ld, half, kt) do {                                    \
    gload_lds16((gb) + (size_t)((half)*128 + 0  + trow) * (ld) + (kt)*64 +    \
                    tslot * 8,                                                \
                (lb) + ((half)*128 + 0) * 64 + wid * 512);                    \
    gload_lds16((gb) + (size_t)((half)*128 + 64 + trow) * (ld) + (kt)*64 +    \
                    tslot * 8,                                                \
                (lb) + ((half)*128 + 64) * 64 + wid * 512);                   \
  } while (0)

#define LDA_H(mh, Ac) do {                                                    \
    _Pragma("unroll") for (int m = 0; m < 4; ++m)                             \
    _Pragma("unroll") for (int kk = 0; kk < 2; ++kk)                          \
      fa[m][kk] = *reinterpret_cast<const short8*>(                           \
          (Ac) + (wr * 128 + (mh)*64 + m * 16 + lr) * 64 +                    \
          (((kk * 4 + lk) ^ rsx) * 8));                                       \
  } while (0)

#define LDB_H(nh, Bc) do {                                                    \
    _Pragma("unroll") for (int n = 0; n < 2; ++n)                             \
    _Pragma("unroll") for (int kk = 0; kk < 2; ++kk)                          \
      fb[(nh)*2 + n][kk] = *reinterpret_cast<const short8*>(                  \
          (Bc) + (wc * 64 + (nh)*32 + n * 16 + lr) * 64 +                     \
          (((kk * 4 + lk) ^ rsx) * 8));                                       \
  } while (0)

#define MFMA_Q(mh, nh) do {                                                   \
    __builtin_amdgcn_s_setprio(1);                                            \
    _Pragma("unroll") for (int m = 0; m < 4; ++m)                             \
    _Pragma("unroll") for (int n = 0; n < 2; ++n)                             \
    _Pragma("unroll") for (int kk = 0; kk < 2; ++kk)                          \
      acc[(mh)*4 + m][(nh)*2 + n] = __builtin_amdgcn_mfma_f32_16x16x32_bf16(  \
          fb[(nh)*2 + n][kk], fa[m][kk], acc[(mh)*4 + m][(nh)*2 + n],         \
          0, 0, 0);                                                           \
    __builtin_amdgcn_s_setprio(0);                                            \
  } while (0)

  STAGE_U(A0, A, lda, 0, 0); STAGE_U(A0, A, lda, 1, 0);
  STAGE_U(B0, B, ldb, 0, 0); STAGE_U(B0, B, ldb, 1, 0);
  STAGE_U(B1, B, ldb, 0, 1); STAGE_U(B1, B, ldb, 1, 1);
  wait_vm<4>();
  __builtin_amdgcn_s_barrier();
  CFENCE;

#pragma unroll 2
  for (int tt = 0; tt < NT; ++tt) {
    const int cur = tt & 1;
    __hip_bfloat16* const Ac = cur ? A1 : A0;
    __hip_bfloat16* const An = cur ? A0 : A1;
    __hip_bfloat16* const Bc = cur ? B1 : B0;
    // c0: quadrant (m0-3, n0-1); stage A-h0(t+1)
    LDA_H(0, Ac); LDB_H(0, Bc);
    if (tt + 1 < NT) STAGE_U(An, A, lda, 0, tt + 1);
    BAR_PRE; MFMA_Q(0, 0); BAR_POST;
    // c1: quadrant (m0-3, n2-3); stage A-h1(t+1)
    LDB_H(1, Bc);
    if (tt + 1 < NT) STAGE_U(An, A, lda, 1, tt + 1);
    BAR_PRE; MFMA_Q(0, 1); BAR_POST;
    // c2: quadrant (m4-7, n2-3); stage B-h0(t+2) (same-parity buffer)
    LDA_H(1, Ac);
    if (tt + 2 < NT) STAGE_U(Bc, B, ldb, 0, tt + 2);
    BAR_PRE; MFMA_Q(1, 1); BAR_POST;
    // c3: quadrant (m4-7, n0-1); stage B-h1(t+2); counted/tail drain
    if (tt + 2 < NT) STAGE_U(Bc, B, ldb, 1, tt + 2);
    BAR_PRE; MFMA_Q(1, 0);
    if (tt + 2 < NT) wait_vm<4>(); else wait_vm<0>();
    BAR_POST;
  }
#undef STAGE_U
#undef LDA_H
#undef LDB_H
#undef MFMA_Q
}

// ------ Q/K projection: X @ W^T + b -> bf16 (vectorized epilogue) ------
// 1-D grid 256, XCD swizzle: xcd owns 4 consecutive bm panels.
__global__ __launch_bounds__(512, 2) void proj_gemm(
    const __hip_bfloat16* __restrict__ X,
    const __hip_bfloat16* __restrict__ Wq, const float* __restrict__ bq,
    const __hip_bfloat16* __restrict__ Wk, const float* __restrict__ bk,
    __hip_bfloat16* __restrict__ Qo, __hip_bfloat16* __restrict__ Ko) {
  extern __shared__ char smem[];
  __hip_bfloat16* lds = reinterpret_cast<__hip_bfloat16*>(smem);
  const int bid = blockIdx.x;
  const int xcd = bid & 7, s = bid >> 3;
  const int bm = xcd * 4 + (s & 3);
  const int bn8 = s >> 2;
  const int z = bn8 >> 2;
  const int bn = bn8 & 3;

  const __hip_bfloat16* W = z ? Wk : Wq;
  const float* bias = z ? bk : bq;
  __hip_bfloat16* Out = z ? Ko : Qo;

  f32x4 acc[8][4];
#pragma unroll
  for (int m = 0; m < 8; ++m)
#pragma unroll
    for (int n = 0; n < 4; ++n) acc[m][n] = (f32x4){0.f, 0.f, 0.f, 0.f};

  gemm_core_bf<HID / 64>(X + (size_t)bm * 256 * HID,
                         W + (size_t)bn * 256 * HID, HID, HID, lds, acc);

  const int t = threadIdx.x, wid = t >> 6, l = t & 63;
  const int wr = wid >> 2, wc = wid & 3;
  const int lr = l & 15, lg = l >> 4;
#pragma unroll
  for (int m = 0; m < 8; ++m) {
    const int row = bm * 256 + wr * 128 + m * 16 + lr;
#pragma unroll
    for (int n = 0; n < 4; ++n) {
      const int col0 = bn * 256 + wc * 64 + n * 16 + lg * 4;
      float4 bb = *reinterpret_cast<const float4*>(&bias[col0]);
      f32x4 a = acc[m][n];
      __hip_bfloat16 tmp[4] = {
          __float2bfloat16(a[0] + bb.x), __float2bfloat16(a[1] + bb.y),
          __float2bfloat16(a[2] + bb.z), __float2bfloat16(a[3] + bb.w)};
      *reinterpret_cast<ushort4*>(&Out[(size_t)row * HID + col0]) =
          *reinterpret_cast<const ushort4*>(tmp);
    }
  }
}

// ---- scores: out[b] = (Q K^T / 128) * mask_r * mask_c (NT stores) ----
// 1-D grid 256; XCD-chunk swizzle (r4-validated decode).
__global__ __launch_bounds__(512, 2) void scores_gemm(
    const __hip_bfloat16* __restrict__ Q, const __hip_bfloat16* __restrict__ Km,
    const float* __restrict__ mask, float* __restrict__ out) {
  extern __shared__ char smem[];
  __hip_bfloat16* lds = reinterpret_cast<__hip_bfloat16*>(smem);
  const int bid = blockIdx.x;
  const int xcd = bid & 7, slot = bid >> 3;
  const int b = slot >> 3, sub = slot & 7;
  const int bm = (xcd & 3) * 2 + (sub >> 2);
  const int bn = (xcd >> 2) * 4 + (sub & 3);

  f32x4 acc[8][4];
#pragma unroll
  for (int m = 0; m < 8; ++m)
#pragma unroll
    for (int n = 0; n < 4; ++n) acc[m][n] = (f32x4){0.f, 0.f, 0.f, 0.f};

  gemm_core_bf<HID / 64>(Q + ((size_t)b * S_LEN + bm * 256) * HID,
                         Km + ((size_t)b * S_LEN + bn * 256) * HID, HID, HID,
                         lds, acc);

  const int t = threadIdx.x, wid = t >> 6, l = t & 63;
  const int wr = wid >> 2, wc = wid & 3;
  const int lr = l & 15, lg = l >> 4;
  const float inv = 1.0f / 128.0f;   // 1/sqrt(64) * 1/16 heads
#pragma unroll
  for (int m = 0; m < 8; ++m) {
    const int row = bm * 256 + wr * 128 + m * 16 + lr;
    const float mr = mask[b * S_LEN + row] * inv;
#pragma unroll
    for (int n = 0; n < 4; ++n) {
      const int col0 = bn * 256 + wc * 64 + n * 16 + lg * 4;
      float4 mcv = *reinterpret_cast<const float4*>(&mask[b * S_LEN + col0]);
      f32x4 a = acc[m][n];
      f32x4 o = {a[0] * mr * mcv.x, a[1] * mr * mcv.y,
                 a[2] * mr * mcv.z, a[3] * mr * mcv.w};
      // output is write-once, never re-read: bypass L2 so Q/K stay resident
      __builtin_nontemporal_store(
          o, reinterpret_cast<f32x4*>(
                 &out[(size_t)b * S_LEN * S_LEN + (size_t)row * S_LEN + col0]));
    }
  }
}

extern "C" void kernel_launch(void* const* d_in, const int* in_sizes, int n_in,
                              void* d_out, int out_size, void* d_ws,
                              size_t ws_size, hipStream_t stream) {
  const float* hs   = (const float*)d_in[0];
  const float* mask = (const float*)d_in[1];
  const float* Wq   = (const float*)d_in[2];
  const float* bq   = (const float*)d_in[3];
  const float* Wk   = (const float*)d_in[4];
  const float* bk   = (const float*)d_in[5];
  float* out = (float*)d_out;

  char* ws = (char*)d_ws;
  __hip_bfloat16* hs_bf = (__hip_bfloat16*)(ws);                 // 16 MB
  __hip_bfloat16* wq_bf = (__hip_bfloat16*)(ws + 16777216);      //  2 MB
  __hip_bfloat16* wk_bf = (__hip_bfloat16*)(ws + 18874368);      //  2 MB
  __hip_bfloat16* q_bf  = (__hip_bfloat16*)(ws + 20971520);      // 16 MB
  __hip_bfloat16* k_bf  = (__hip_bfloat16*)(ws + 37748736);      // 16 MB

  (void)hipFuncSetAttribute((const void*)proj_gemm,
                            hipFuncAttributeMaxDynamicSharedMemorySize, 131072);
  (void)hipFuncSetAttribute((const void*)scores_gemm,
                            hipFuncAttributeMaxDynamicSharedMemorySize, 131072);

  hipLaunchKernelGGL(convert_all, dim3(10240), dim3(256), 0, stream,
                     hs, Wq, Wk, hs_bf, wq_bf, wk_bf);
  hipLaunchKernelGGL(proj_gemm, dim3(256), dim3(512), 131072, stream,
                     hs_bf, wq_bf, bq, wk_bf, bk, q_bf, k_bf);
  hipLaunchKernelGGL(scores_gemm, dim3(256), dim3(512), 131072, stream,
                     q_bf, k_bf, mask, out);
}